// Round 1
// baseline (378.470 us; speedup 1.0000x reference)
//
#include <hip/hip_runtime.h>

#define RAD   1
#define EPS_F 0.01f
#define LR_H  512
#define LR_W  512
#define HR_H  2048
#define HR_W  2048
#define NC    12   // N*C = 4*3

#define LR_PLANE (LR_H * LR_W)
#define HR_PLANE (HR_H * HR_W)
#define LR_TOTAL (NC * LR_PLANE)
#define HR_TOTAL (NC * HR_PLANE)

// K1: fused 3x3 edge-replicated box stats -> A, b
__global__ void __launch_bounds__(256) k_compute_Ab(
    const float* __restrict__ x, const float* __restrict__ y,
    float* __restrict__ A, float* __restrict__ b) {
    int idx = blockIdx.x * blockDim.x + threadIdx.x;
    if (idx >= LR_TOTAL) return;
    int w = idx & (LR_W - 1);
    int h = (idx >> 9) & (LR_H - 1);
    int plane = idx >> 18;
    const float* xp = x + (size_t)plane * LR_PLANE;
    const float* yp = y + (size_t)plane * LR_PLANE;

    float sx = 0.f, sy = 0.f, sxy = 0.f, sxx = 0.f;
#pragma unroll
    for (int di = -1; di <= 1; ++di) {
        int hh = min(max(h + di, 0), LR_H - 1);
        int rowoff = hh * LR_W;
#pragma unroll
        for (int dj = -1; dj <= 1; ++dj) {
            int ww = min(max(w + dj, 0), LR_W - 1);
            float xv = xp[rowoff + ww];
            float yv = yp[rowoff + ww];
            sx  += xv;
            sy  += yv;
            sxy += xv * yv;
            sxx += xv * xv;
        }
    }
    const float inv9 = 1.0f / 9.0f;
    float mx  = sx  * inv9;
    float my  = sy  * inv9;
    float cov = sxy * inv9 - mx * my;
    float var = sxx * inv9 - mx * mx;
    float Av  = cov / (var + EPS_F);
    float bv  = my - Av * mx;
    A[idx] = Av;
    b[idx] = bv;
}

// K2: 3x3 edge-replicated box mean of A and b -> mA, mb
__global__ void __launch_bounds__(256) k_box_Ab(
    const float* __restrict__ A, const float* __restrict__ b,
    float* __restrict__ mA, float* __restrict__ mb) {
    int idx = blockIdx.x * blockDim.x + threadIdx.x;
    if (idx >= LR_TOTAL) return;
    int w = idx & (LR_W - 1);
    int h = (idx >> 9) & (LR_H - 1);
    int plane = idx >> 18;
    const float* Ap = A + (size_t)plane * LR_PLANE;
    const float* bp = b + (size_t)plane * LR_PLANE;

    float sA = 0.f, sB = 0.f;
#pragma unroll
    for (int di = -1; di <= 1; ++di) {
        int hh = min(max(h + di, 0), LR_H - 1);
        int rowoff = hh * LR_W;
#pragma unroll
        for (int dj = -1; dj <= 1; ++dj) {
            int ww = min(max(w + dj, 0), LR_W - 1);
            sA += Ap[rowoff + ww];
            sB += bp[rowoff + ww];
        }
    }
    const float inv9 = 1.0f / 9.0f;
    mA[idx] = sA * inv9;
    mb[idx] = sB * inv9;
}

// K3: bilinear (align_corners=True) upsample of mA/mb fused with
// clip(mA_up * x_hr + mb_up, 0, 255). 4 HR pixels per thread (float4).
__global__ void __launch_bounds__(256) k_upsample_fuse(
    const float* __restrict__ mA, const float* __restrict__ mb,
    const float* __restrict__ xhr, float* __restrict__ out) {
    int vid = blockIdx.x * blockDim.x + threadIdx.x;   // vector id (4 px)
    if (vid >= HR_TOTAL / 4) return;
    int idx = vid * 4;
    int j0base = idx & (HR_W - 1);
    int i      = (idx >> 11) & (HR_H - 1);
    int plane  = idx >> 22;

    const float scale_h = (float)(LR_H - 1) / (float)(HR_H - 1);
    const float scale_w = (float)(LR_W - 1) / (float)(HR_W - 1);

    float ph = i * scale_h;
    int   i0 = (int)floorf(ph);
    int   i1 = min(i0 + 1, LR_H - 1);
    float th = ph - (float)i0;

    const float* Ap = mA + (size_t)plane * LR_PLANE;
    const float* bp = mb + (size_t)plane * LR_PLANE;
    const float4 xv = *(const float4*)(xhr + idx);
    float4 r;

    float res[4];
    float xin[4] = {xv.x, xv.y, xv.z, xv.w};
#pragma unroll
    for (int k = 0; k < 4; ++k) {
        int jj = j0base + k;
        float pw = jj * scale_w;
        int   j0 = (int)floorf(pw);
        int   j1 = min(j0 + 1, LR_W - 1);
        float tw = pw - (float)j0;

        // H-axis lerp first (matches reference), then W-axis
        float a_l = Ap[i0 * LR_W + j0] * (1.f - th) + Ap[i1 * LR_W + j0] * th;
        float a_r = Ap[i0 * LR_W + j1] * (1.f - th) + Ap[i1 * LR_W + j1] * th;
        float a_v = a_l * (1.f - tw) + a_r * tw;

        float b_l = bp[i0 * LR_W + j0] * (1.f - th) + bp[i1 * LR_W + j0] * th;
        float b_r = bp[i0 * LR_W + j1] * (1.f - th) + bp[i1 * LR_W + j1] * th;
        float b_v = b_l * (1.f - tw) + b_r * tw;

        float v = a_v * xin[k] + b_v;
        res[k] = fminf(fmaxf(v, 0.0f), 255.0f);
    }
    r.x = res[0]; r.y = res[1]; r.z = res[2]; r.w = res[3];
    *(float4*)(out + idx) = r;
}

extern "C" void kernel_launch(void* const* d_in, const int* in_sizes, int n_in,
                              void* d_out, int out_size, void* d_ws, size_t ws_size,
                              hipStream_t stream) {
    const float* x_lr = (const float*)d_in[0];
    const float* y_lr = (const float*)d_in[1];
    const float* x_hr = (const float*)d_in[2];
    float* out = (float*)d_out;

    float* A  = (float*)d_ws;
    float* b  = A  + LR_TOTAL;
    float* mA = b  + LR_TOTAL;
    float* mb = mA + LR_TOTAL;

    {
        int threads = 256;
        int blocks = (LR_TOTAL + threads - 1) / threads;
        k_compute_Ab<<<blocks, threads, 0, stream>>>(x_lr, y_lr, A, b);
        k_box_Ab<<<blocks, threads, 0, stream>>>(A, b, mA, mb);
    }
    {
        int threads = 256;
        int blocks = (HR_TOTAL / 4 + threads - 1) / threads;
        k_upsample_fuse<<<blocks, threads, 0, stream>>>(mA, mb, x_hr, out);
    }
}

// Round 2
// 372.213 us; speedup vs baseline: 1.0168x; 1.0168x over previous
//
#include <hip/hip_runtime.h>

#define RAD   1
#define EPS_F 0.01f
#define LR_H  512
#define LR_W  512
#define HR_H  2048
#define HR_W  2048
#define NC    12   // N*C = 4*3

#define LR_PLANE (LR_H * LR_W)
#define HR_PLANE (HR_H * HR_W)
#define LR_TOTAL (NC * LR_PLANE)
#define HR_TOTAL (NC * HR_PLANE)

// K1: fused 3x3 edge-replicated box stats -> A, b
__global__ void __launch_bounds__(256) k_compute_Ab(
    const float* __restrict__ x, const float* __restrict__ y,
    float* __restrict__ A, float* __restrict__ b) {
    int idx = blockIdx.x * blockDim.x + threadIdx.x;
    if (idx >= LR_TOTAL) return;
    int w = idx & (LR_W - 1);
    int h = (idx >> 9) & (LR_H - 1);
    int plane = idx >> 18;
    const float* xp = x + (size_t)plane * LR_PLANE;
    const float* yp = y + (size_t)plane * LR_PLANE;

    float sx = 0.f, sy = 0.f, sxy = 0.f, sxx = 0.f;
#pragma unroll
    for (int di = -1; di <= 1; ++di) {
        int hh = min(max(h + di, 0), LR_H - 1);
        int rowoff = hh * LR_W;
#pragma unroll
        for (int dj = -1; dj <= 1; ++dj) {
            int ww = min(max(w + dj, 0), LR_W - 1);
            float xv = xp[rowoff + ww];
            float yv = yp[rowoff + ww];
            sx  += xv;
            sy  += yv;
            sxy += xv * yv;
            sxx += xv * xv;
        }
    }
    const float inv9 = 1.0f / 9.0f;
    float mx  = sx  * inv9;
    float my  = sy  * inv9;
    float cov = sxy * inv9 - mx * my;
    float var = sxx * inv9 - mx * mx;
    float Av  = cov / (var + EPS_F);
    float bv  = my - Av * mx;
    A[idx] = Av;
    b[idx] = bv;
}

// K2: 3x3 edge-replicated box mean of A and b -> mA, mb
__global__ void __launch_bounds__(256) k_box_Ab(
    const float* __restrict__ A, const float* __restrict__ b,
    float* __restrict__ mA, float* __restrict__ mb) {
    int idx = blockIdx.x * blockDim.x + threadIdx.x;
    if (idx >= LR_TOTAL) return;
    int w = idx & (LR_W - 1);
    int h = (idx >> 9) & (LR_H - 1);
    int plane = idx >> 18;
    const float* Ap = A + (size_t)plane * LR_PLANE;
    const float* bp = b + (size_t)plane * LR_PLANE;

    float sA = 0.f, sB = 0.f;
#pragma unroll
    for (int di = -1; di <= 1; ++di) {
        int hh = min(max(h + di, 0), LR_H - 1);
        int rowoff = hh * LR_W;
#pragma unroll
        for (int dj = -1; dj <= 1; ++dj) {
            int ww = min(max(w + dj, 0), LR_W - 1);
            sA += Ap[rowoff + ww];
            sB += bp[rowoff + ww];
        }
    }
    const float inv9 = 1.0f / 9.0f;
    mA[idx] = sA * inv9;
    mb[idx] = sB * inv9;
}

// K3 v2: one block per (plane, HR row). Stage H-lerped LR rows of mA/mb in
// LDS (hA/hb, 513 wide with duplicated last col), then per-pixel W-lerp +
// fused FMA/clip. No global gathers in the pixel loop.
__global__ void __launch_bounds__(256) k_upsample_fuse(
    const float* __restrict__ mA, const float* __restrict__ mb,
    const float* __restrict__ xhr, float* __restrict__ out) {
    __shared__ float hA[513];
    __shared__ float hb[513];

    int bid = blockIdx.x;                 // plane * HR_H + i
    int i     = bid & (HR_H - 1);
    int plane = bid >> 11;

    const float scale = (float)(LR_H - 1) / (float)(HR_H - 1);

    float ph = i * scale;
    int   i0 = (int)ph;                   // ph >= 0 -> trunc == floor
    int   i1 = min(i0 + 1, LR_H - 1);
    float th = ph - (float)i0;
    float omh = 1.0f - th;

    const float* Ap = mA + (size_t)plane * LR_PLANE;
    const float* bp = mb + (size_t)plane * LR_PLANE;
    int tid = threadIdx.x;

    for (int c = tid; c < 513; c += 256) {
        int col = min(c, LR_W - 1);
        float a0 = Ap[i0 * LR_W + col];
        float a1 = Ap[i1 * LR_W + col];
        float b0 = bp[i0 * LR_W + col];
        float b1 = bp[i1 * LR_W + col];
        hA[c] = a0 * omh + a1 * th;
        hb[c] = b0 * omh + b1 * th;
    }
    __syncthreads();

    const float* xrow = xhr + (size_t)plane * HR_PLANE + (size_t)i * HR_W;
    float*       orow = out + (size_t)plane * HR_PLANE + (size_t)i * HR_W;

#pragma unroll
    for (int g = 0; g < 2; ++g) {
        int j = (tid + g * 256) * 4;
        const float4 xv = *(const float4*)(xrow + j);
        float xin[4] = {xv.x, xv.y, xv.z, xv.w};
        float r[4];
#pragma unroll
        for (int k = 0; k < 4; ++k) {
            float pw = (float)(j + k) * scale;
            int   j0 = (int)pw;
            float tw = pw - (float)j0;
            float omw = 1.0f - tw;
            float a  = hA[j0] * omw + hA[j0 + 1] * tw;
            float bb = hb[j0] * omw + hb[j0 + 1] * tw;
            float v  = a * xin[k] + bb;
            r[k] = fminf(fmaxf(v, 0.0f), 255.0f);
        }
        float4 o;
        o.x = r[0]; o.y = r[1]; o.z = r[2]; o.w = r[3];
        *(float4*)(orow + j) = o;
    }
}

extern "C" void kernel_launch(void* const* d_in, const int* in_sizes, int n_in,
                              void* d_out, int out_size, void* d_ws, size_t ws_size,
                              hipStream_t stream) {
    const float* x_lr = (const float*)d_in[0];
    const float* y_lr = (const float*)d_in[1];
    const float* x_hr = (const float*)d_in[2];
    float* out = (float*)d_out;

    float* A  = (float*)d_ws;
    float* b  = A  + LR_TOTAL;
    float* mA = b  + LR_TOTAL;
    float* mb = mA + LR_TOTAL;

    {
        int threads = 256;
        int blocks = (LR_TOTAL + threads - 1) / threads;
        k_compute_Ab<<<blocks, threads, 0, stream>>>(x_lr, y_lr, A, b);
        k_box_Ab<<<blocks, threads, 0, stream>>>(A, b, mA, mb);
    }
    {
        int threads = 256;
        int blocks = NC * HR_H;   // one block per HR row per plane
        k_upsample_fuse<<<blocks, threads, 0, stream>>>(mA, mb, x_hr, out);
    }
}